// Round 13
// baseline (317.684 us; speedup 1.0000x reference)
//
#include <hip/hip_runtime.h>

#define NN 100000
#define D 64
#define G 3        // node-range groups (hist/fill)
#define RS 33334   // nodes per range (G*RS >= NN)
#define NC 85      // edge chunks
#define NB (G*NC)  // 255 blocks for hist/fill

typedef short bf16x8 __attribute__((ext_vector_type(8)));
typedef float f32x4 __attribute__((ext_vector_type(4)));
typedef float f32x2 __attribute__((ext_vector_type(2)));

// ---- bf16 helpers ----
__device__ __forceinline__ float bf2f_lo(unsigned w) { return __uint_as_float(w << 16); }
__device__ __forceinline__ float bf2f_hi(unsigned w) { return __uint_as_float(w & 0xffff0000u); }
__device__ __forceinline__ unsigned short f2bf(float f) {
    unsigned u = __float_as_uint(f);
    return (unsigned short)((u + 0x7fffu + ((u >> 16) & 1u)) >> 16);
}
__device__ __forceinline__ unsigned pack2(float a, float b) {
    return (unsigned)f2bf(a) | ((unsigned)f2bf(b) << 16);
}
// ---- fp8 e4m3 helpers (HW cvt) ----
__device__ __forceinline__ unsigned char f2fp8(float v) {
    return (unsigned char)(__builtin_amdgcn_cvt_pk_fp8_f32(v, v, 0, false) & 0xff);
}
// ---- packed edge record: bits 0-16 = src, bits 17-31 = bf16(w) sans sign ----
__device__ __forceinline__ unsigned pack_cw(int s, float w) {
    return ((unsigned)f2bf(w) << 17) | (unsigned)s;
}
// ---- packed f32 FMA: acc += w2 * p (VOP3P v_pk_fma_f32) ----
#define PKFMA(acc, w2, p) \
    asm("v_pk_fma_f32 %0, %1, %2, %0" : "+v"(acc) : "v"(w2), "v"(p))

// ---- byte-packed LDS histogram: word k = nodes 2k,2k+1; per node (src,dst) bytes ----
__global__ __launch_bounds__(1024) void k_hist(const int* __restrict__ src,
                                               const int* __restrict__ dst,
                                               unsigned short* __restrict__ psd, int E) {
    __shared__ unsigned h[RS / 2];
    int b = blockIdx.x, t = threadIdx.x;
    int g = b / NC, c = b - g * NC;
    int lo = g * RS;
    for (int i = t; i < RS / 2; i += 1024) h[i] = 0;
    __syncthreads();
    int e0 = (int)((((long long)c * E / NC)) & ~3LL);
    int e1 = (c == NC - 1) ? E : (int)((((long long)(c + 1) * E / NC)) & ~3LL);
    int m = (e1 - e0) & ~4095;
    for (int e = e0 + t * 4; e < e0 + m; e += 4096) {
        int4 s4 = *(const int4*)(src + e);
        int4 d4 = *(const int4*)(dst + e);
        int v;
        v = s4.x - lo; if ((unsigned)v < RS) atomicAdd(&h[v >> 1], 1u << ((v & 1) * 16));
        v = s4.y - lo; if ((unsigned)v < RS) atomicAdd(&h[v >> 1], 1u << ((v & 1) * 16));
        v = s4.z - lo; if ((unsigned)v < RS) atomicAdd(&h[v >> 1], 1u << ((v & 1) * 16));
        v = s4.w - lo; if ((unsigned)v < RS) atomicAdd(&h[v >> 1], 1u << ((v & 1) * 16));
        v = d4.x - lo; if ((unsigned)v < RS) atomicAdd(&h[v >> 1], 1u << ((v & 1) * 16 + 8));
        v = d4.y - lo; if ((unsigned)v < RS) atomicAdd(&h[v >> 1], 1u << ((v & 1) * 16 + 8));
        v = d4.z - lo; if ((unsigned)v < RS) atomicAdd(&h[v >> 1], 1u << ((v & 1) * 16 + 8));
        v = d4.w - lo; if ((unsigned)v < RS) atomicAdd(&h[v >> 1], 1u << ((v & 1) * 16 + 8));
    }
    for (int e = e0 + m + t; e < e1; e += 1024) {
        int v = src[e] - lo; if ((unsigned)v < RS) atomicAdd(&h[v >> 1], 1u << ((v & 1) * 16));
        v = dst[e] - lo;     if ((unsigned)v < RS) atomicAdd(&h[v >> 1], 1u << ((v & 1) * 16 + 8));
    }
    __syncthreads();
    unsigned* pb = (unsigned*)(psd + (size_t)b * RS);
    for (int i = t; i < RS / 2; i += 1024) pb[i] = h[i];
}

// ---- merge byte partials -> norms; block-scan 1024 in-degrees -> rowptr partial ----
__global__ __launch_bounds__(1024) void k_scan1m(const unsigned short* __restrict__ psd,
                                                 float* __restrict__ ns, float* __restrict__ nd,
                                                 int* __restrict__ rowptr,
                                                 int* __restrict__ bsum, int n) {
    __shared__ int lds[1024];
    int t = threadIdx.x;
    int i = blockIdx.x * 1024 + t;
    int sv = 0, dv = 0;
    if (i < n) {
        int g = i / RS, off = i - g * RS;
        const unsigned short* p = psd + (size_t)(g * NC) * RS + off;
        #pragma unroll 5
        for (int c = 0; c < NC; ++c) {
            unsigned v = p[(size_t)c * RS];
            sv += (int)(v & 0xffu);
            dv += (int)(v >> 8);
        }
        ns[i] = rsqrtf(fmaxf((float)sv, 1.0f));
        nd[i] = rsqrtf(fmaxf((float)dv, 1.0f));
    }
    lds[t] = dv;
    __syncthreads();
    for (int off = 1; off < 1024; off <<= 1) {
        int v = lds[t];
        int a = (t >= off) ? lds[t - off] : 0;
        __syncthreads();
        lds[t] = v + a;
        __syncthreads();
    }
    if (t == 1023) bsum[blockIdx.x] = lds[1023];
    if (i < n) rowptr[i] = lds[t] - dv;   // exclusive
}

// ---- finalize rowptr + write 16-bit within-segment cursors; bsum scan fused ----
__global__ void k_scan3c(int* __restrict__ rowptr, const int* __restrict__ bsum,
                         const unsigned short* __restrict__ psd,
                         unsigned short* __restrict__ cur16,
                         int n, int E, int nb) {
    __shared__ int sbs[128];
    int t = threadIdx.x;
    if (t < 128) sbs[t] = (t < nb) ? bsum[t] : 0;
    __syncthreads();
    for (int off = 1; off < 128; off <<= 1) {
        int v = 0, a = 0;
        if (t < 128) { v = sbs[t]; if (t >= off) a = sbs[t - off]; }
        __syncthreads();
        if (t < 128) sbs[t] = v + a;
        __syncthreads();
    }
    int i = blockIdx.x * blockDim.x + t;
    if (i == 0) rowptr[n] = E;
    if (i >= n) return;
    int blk = i >> 10;
    int base = (blk > 0) ? sbs[blk - 1] : 0;
    int r = rowptr[i] + base;
    rowptr[i] = r;
    int g = i / RS, off = i - g * RS;
    const unsigned short* p = psd + (size_t)(g * NC) * RS + off;
    unsigned short* cp = cur16 + (size_t)(g * NC) * RS + off;
    int run = 0;
    #pragma unroll 5
    for (int c = 0; c < NC; ++c) {
        cp[(size_t)c * RS] = (unsigned short)run;
        run += (int)(p[(size_t)c * RS] >> 8);
    }
}

// ---- counting-sort fill: LDS cursors = rowptr + 16-bit offsets; 4B packed records ----
__global__ __launch_bounds__(1024) void k_fillsort(const int* __restrict__ src,
                                                   const int* __restrict__ dst,
                                                   const float* __restrict__ ew,
                                                   const int* __restrict__ rowptr,
                                                   const unsigned short* __restrict__ cur16,
                                                   unsigned* __restrict__ cw, int E) {
    __shared__ int cur[RS];
    int b = blockIdx.x, t = threadIdx.x;
    int g = b / NC, c = b - g * NC;
    int lo = g * RS;
    const unsigned short* c16 = cur16 + (size_t)b * RS;
    for (int i = t; i < RS; i += 1024) cur[i] = rowptr[lo + i] + (int)c16[i];
    __syncthreads();
    int e0 = (int)((((long long)c * E / NC)) & ~3LL);
    int e1 = (c == NC - 1) ? E : (int)((((long long)(c + 1) * E / NC)) & ~3LL);
    int m = (e1 - e0) & ~4095;
    for (int e = e0 + t * 4; e < e0 + m; e += 4096) {
        int4 s4 = *(const int4*)(src + e);
        int4 d4 = *(const int4*)(dst + e);
        float4 w4 = *(const float4*)(ew + e);
        int d;
        d = d4.x - lo; if ((unsigned)d < RS) { int p = atomicAdd(&cur[d], 1); cw[p] = pack_cw(s4.x, w4.x); }
        d = d4.y - lo; if ((unsigned)d < RS) { int p = atomicAdd(&cur[d], 1); cw[p] = pack_cw(s4.y, w4.y); }
        d = d4.z - lo; if ((unsigned)d < RS) { int p = atomicAdd(&cur[d], 1); cw[p] = pack_cw(s4.z, w4.z); }
        d = d4.w - lo; if ((unsigned)d < RS) { int p = atomicAdd(&cur[d], 1); cw[p] = pack_cw(s4.w, w4.w); }
    }
    for (int e = e0 + m + t; e < e1; e += 1024) {
        int d = dst[e] - lo;
        if ((unsigned)d < RS) {
            int p = atomicAdd(&cur[d], 1);
            cw[p] = pack_cw(src[e], ew[e]);
        }
    }
}

// ---- fused first stage: res = bf16(X@Wr + br), tmat1 = fp8((ns*X)@W1) ----
__global__ __launch_bounds__(256) void k_gemm2(const float* __restrict__ x,
                                               const float* __restrict__ Wr,
                                               const float* __restrict__ brs,
                                               const float* __restrict__ W1,
                                               const float* __restrict__ ns,
                                               unsigned short* __restrict__ resb,
                                               unsigned char* __restrict__ tmat, int n) {
    __shared__ unsigned short WTr[64][72];
    __shared__ unsigned short WT1[64][72];
    int t = threadIdx.x;
    for (int i = t; i < 64 * 64; i += 256) {
        int k = i >> 6, nn = i & 63;      // W row-major [k][nn], coalesced
        WTr[nn][k] = f2bf(Wr[i]);
        WT1[nn][k] = f2bf(W1[i]);
    }
    __syncthreads();
    int w = t >> 6, lane = t & 63;
    int m = lane & 15, q = lane >> 4;
    int node0 = blockIdx.x * 64 + w * 16;
    int nodeA = min(node0 + m, n - 1);
    const float* inf = x + (size_t)nodeA * D;
    float sc = ns[nodeA];
    bf16x8 afr[2], afs[2];
    #pragma unroll
    for (int kc = 0; kc < 2; ++kc) {
        float4 f0 = *(const float4*)(inf + kc * 32 + q * 8);
        float4 f1 = *(const float4*)(inf + kc * 32 + q * 8 + 4);
        union { bf16x8 v; unsigned short u[8]; } ta, ts;
        ta.u[0] = f2bf(f0.x); ta.u[1] = f2bf(f0.y);
        ta.u[2] = f2bf(f0.z); ta.u[3] = f2bf(f0.w);
        ta.u[4] = f2bf(f1.x); ta.u[5] = f2bf(f1.y);
        ta.u[6] = f2bf(f1.z); ta.u[7] = f2bf(f1.w);
        ts.u[0] = f2bf(f0.x * sc); ts.u[1] = f2bf(f0.y * sc);
        ts.u[2] = f2bf(f0.z * sc); ts.u[3] = f2bf(f0.w * sc);
        ts.u[4] = f2bf(f1.x * sc); ts.u[5] = f2bf(f1.y * sc);
        ts.u[6] = f2bf(f1.z * sc); ts.u[7] = f2bf(f1.w * sc);
        afr[kc] = ta.v;
        afs[kc] = ts.v;
    }
    #pragma unroll
    for (int nt = 0; nt < 4; ++nt) {
        f32x4 ar = {0.f, 0.f, 0.f, 0.f};
        f32x4 at = {0.f, 0.f, 0.f, 0.f};
        #pragma unroll
        for (int kc = 0; kc < 2; ++kc) {
            union { bf16x8 v; uint4 u; } bfr, bf1;
            bfr.u = *(const uint4*)&WTr[nt * 16 + m][kc * 32 + q * 8];
            bf1.u = *(const uint4*)&WT1[nt * 16 + m][kc * 32 + q * 8];
            ar = __builtin_amdgcn_mfma_f32_16x16x32_bf16(afr[kc], bfr.v, ar, 0, 0, 0);
            at = __builtin_amdgcn_mfma_f32_16x16x32_bf16(afs[kc], bf1.v, at, 0, 0, 0);
        }
        int col = nt * 16 + m;
        float bb = brs[col];
        #pragma unroll
        for (int r = 0; r < 4; ++r) {
            int node = node0 + q * 4 + r;
            if (node < n) {
                resb[(size_t)node * D + col] = f2bf(ar[r] + bb);
                tmat[(size_t)node * D + col] = f2fp8(at[r]);
            }
        }
    }
}

// ---- gather-reduce + epilogue: 8 LANES per node (8 nodes/wave), 8-edge-deep loop;
// ---- 8 rows in flight per group; cw prefetched one iteration ahead; pk_fma ----
// __launch_bounds__(256,8): cap VGPR at 64 to hold 8 waves/SIMD (32 waves/CU)
template<bool LAST>
__global__ __launch_bounds__(256, 8) void k_gather(
                         const int* __restrict__ rowptr, const unsigned* __restrict__ cw,
                         const unsigned char* __restrict__ tmat,
                         const float* __restrict__ nd, const float* __restrict__ ns,
                         const float* __restrict__ bias,
                         const unsigned short* __restrict__ resb,
                         unsigned short* __restrict__ outb, int n, int E) {
    int grp = threadIdx.x >> 3;            // node group in block (0..31)
    int h   = threadIdx.x & 7;             // feature octet
    int node = blockIdx.x * 32 + grp;
    bool valid = node < n;
    int nc = valid ? node : 0;
    int beg = rowptr[nc];
    int end = valid ? rowptr[nc + 1] : beg;
    unsigned h8 = (unsigned)(h * 8);
    f32x2 A0={0.f,0.f},A1={0.f,0.f},A2={0.f,0.f},A3={0.f,0.f};
    f32x2 C0={0.f,0.f},C1={0.f,0.f},C2={0.f,0.f},C3={0.f,0.f};
    unsigned cv0 = (beg     < end) ? cw[beg]     : 0u;
    unsigned cv1 = (beg + 1 < end) ? cw[beg + 1] : 0u;
    unsigned cv2 = (beg + 2 < end) ? cw[beg + 2] : 0u;
    unsigned cv3 = (beg + 3 < end) ? cw[beg + 3] : 0u;
    unsigned cv4 = (beg + 4 < end) ? cw[beg + 4] : 0u;
    unsigned cv5 = (beg + 5 < end) ? cw[beg + 5] : 0u;
    unsigned cv6 = (beg + 6 < end) ? cw[beg + 6] : 0u;
    unsigned cv7 = (beg + 7 < end) ? cw[beg + 7] : 0u;
    for (int e = beg; e < end; e += 8) {
        // 8 tmat rows in flight (uniform base + 32-bit voffset)
        uint2 r0 = *(const uint2*)(tmat + (((cv0 & 0x1FFFFu) << 6) + h8));
        uint2 r1 = *(const uint2*)(tmat + (((cv1 & 0x1FFFFu) << 6) + h8));
        uint2 r2 = *(const uint2*)(tmat + (((cv2 & 0x1FFFFu) << 6) + h8));
        uint2 r3 = *(const uint2*)(tmat + (((cv3 & 0x1FFFFu) << 6) + h8));
        uint2 r4 = *(const uint2*)(tmat + (((cv4 & 0x1FFFFu) << 6) + h8));
        uint2 r5 = *(const uint2*)(tmat + (((cv5 & 0x1FFFFu) << 6) + h8));
        uint2 r6 = *(const uint2*)(tmat + (((cv6 & 0x1FFFFu) << 6) + h8));
        uint2 r7 = *(const uint2*)(tmat + (((cv7 & 0x1FFFFu) << 6) + h8));
        // weights decoded before cv regs are overwritten by prefetch
        float w0 = __uint_as_float((cv0 >> 17) << 16);
        float w1 = __uint_as_float((cv1 >> 17) << 16);
        float w2 = __uint_as_float((cv2 >> 17) << 16);
        float w3 = __uint_as_float((cv3 >> 17) << 16);
        float w4 = __uint_as_float((cv4 >> 17) << 16);
        float w5 = __uint_as_float((cv5 >> 17) << 16);
        float w6 = __uint_as_float((cv6 >> 17) << 16);
        float w7 = __uint_as_float((cv7 >> 17) << 16);
        // prefetch next iteration's edge records
        int f = e + 8;
        cv0 = (f     < end) ? cw[f]     : 0u;
        cv1 = (f + 1 < end) ? cw[f + 1] : 0u;
        cv2 = (f + 2 < end) ? cw[f + 2] : 0u;
        cv3 = (f + 3 < end) ? cw[f + 3] : 0u;
        cv4 = (f + 4 < end) ? cw[f + 4] : 0u;
        cv5 = (f + 5 < end) ? cw[f + 5] : 0u;
        cv6 = (f + 6 < end) ? cw[f + 6] : 0u;
        cv7 = (f + 7 < end) ? cw[f + 7] : 0u;
        f32x2 p, wv;
        wv.x = w0; wv.y = w0;
        p = __builtin_amdgcn_cvt_pk_f32_fp8(r0.x, false); PKFMA(A0, wv, p);
        p = __builtin_amdgcn_cvt_pk_f32_fp8(r0.x, true);  PKFMA(A1, wv, p);
        p = __builtin_amdgcn_cvt_pk_f32_fp8(r0.y, false); PKFMA(A2, wv, p);
        p = __builtin_amdgcn_cvt_pk_f32_fp8(r0.y, true);  PKFMA(A3, wv, p);
        wv.x = w1; wv.y = w1;
        p = __builtin_amdgcn_cvt_pk_f32_fp8(r1.x, false); PKFMA(C0, wv, p);
        p = __builtin_amdgcn_cvt_pk_f32_fp8(r1.x, true);  PKFMA(C1, wv, p);
        p = __builtin_amdgcn_cvt_pk_f32_fp8(r1.y, false); PKFMA(C2, wv, p);
        p = __builtin_amdgcn_cvt_pk_f32_fp8(r1.y, true);  PKFMA(C3, wv, p);
        wv.x = w2; wv.y = w2;
        p = __builtin_amdgcn_cvt_pk_f32_fp8(r2.x, false); PKFMA(A0, wv, p);
        p = __builtin_amdgcn_cvt_pk_f32_fp8(r2.x, true);  PKFMA(A1, wv, p);
        p = __builtin_amdgcn_cvt_pk_f32_fp8(r2.y, false); PKFMA(A2, wv, p);
        p = __builtin_amdgcn_cvt_pk_f32_fp8(r2.y, true);  PKFMA(A3, wv, p);
        wv.x = w3; wv.y = w3;
        p = __builtin_amdgcn_cvt_pk_f32_fp8(r3.x, false); PKFMA(C0, wv, p);
        p = __builtin_amdgcn_cvt_pk_f32_fp8(r3.x, true);  PKFMA(C1, wv, p);
        p = __builtin_amdgcn_cvt_pk_f32_fp8(r3.y, false); PKFMA(C2, wv, p);
        p = __builtin_amdgcn_cvt_pk_f32_fp8(r3.y, true);  PKFMA(C3, wv, p);
        wv.x = w4; wv.y = w4;
        p = __builtin_amdgcn_cvt_pk_f32_fp8(r4.x, false); PKFMA(A0, wv, p);
        p = __builtin_amdgcn_cvt_pk_f32_fp8(r4.x, true);  PKFMA(A1, wv, p);
        p = __builtin_amdgcn_cvt_pk_f32_fp8(r4.y, false); PKFMA(A2, wv, p);
        p = __builtin_amdgcn_cvt_pk_f32_fp8(r4.y, true);  PKFMA(A3, wv, p);
        wv.x = w5; wv.y = w5;
        p = __builtin_amdgcn_cvt_pk_f32_fp8(r5.x, false); PKFMA(C0, wv, p);
        p = __builtin_amdgcn_cvt_pk_f32_fp8(r5.x, true);  PKFMA(C1, wv, p);
        p = __builtin_amdgcn_cvt_pk_f32_fp8(r5.y, false); PKFMA(C2, wv, p);
        p = __builtin_amdgcn_cvt_pk_f32_fp8(r5.y, true);  PKFMA(C3, wv, p);
        wv.x = w6; wv.y = w6;
        p = __builtin_amdgcn_cvt_pk_f32_fp8(r6.x, false); PKFMA(A0, wv, p);
        p = __builtin_amdgcn_cvt_pk_f32_fp8(r6.x, true);  PKFMA(A1, wv, p);
        p = __builtin_amdgcn_cvt_pk_f32_fp8(r6.y, false); PKFMA(A2, wv, p);
        p = __builtin_amdgcn_cvt_pk_f32_fp8(r6.y, true);  PKFMA(A3, wv, p);
        wv.x = w7; wv.y = w7;
        p = __builtin_amdgcn_cvt_pk_f32_fp8(r7.x, false); PKFMA(C0, wv, p);
        p = __builtin_amdgcn_cvt_pk_f32_fp8(r7.x, true);  PKFMA(C1, wv, p);
        p = __builtin_amdgcn_cvt_pk_f32_fp8(r7.y, false); PKFMA(C2, wv, p);
        p = __builtin_amdgcn_cvt_pk_f32_fp8(r7.y, true);  PKFMA(C3, wv, p);
    }
    if (!valid) return;
    float a0 = A0.x + C0.x, a1 = A0.y + C0.y;
    float a2 = A1.x + C1.x, a3 = A1.y + C1.y;
    float a4 = A2.x + C2.x, a5 = A2.y + C2.y;
    float a6 = A3.x + C3.x, a7 = A3.y + C3.y;
    float ndv = nd[node];
    float4 b0 = *(const float4*)(bias + 8 * h);
    float4 b1 = *(const float4*)(bias + 8 * h + 4);
    float v0 = ndv * a0 + b0.x, v1 = ndv * a1 + b0.y;
    float v2 = ndv * a2 + b0.z, v3 = ndv * a3 + b0.w;
    float v4 = ndv * a4 + b1.x, v5 = ndv * a5 + b1.y;
    float v6 = ndv * a6 + b1.z, v7 = ndv * a7 + b1.w;
    if (LAST) {
        uint4 r = *((const uint4*)(resb + (size_t)node * D) + h);
        v0 += bf2f_lo(r.x); v1 += bf2f_hi(r.x);
        v2 += bf2f_lo(r.y); v3 += bf2f_hi(r.y);
        v4 += bf2f_lo(r.z); v5 += bf2f_hi(r.z);
        v6 += bf2f_lo(r.w); v7 += bf2f_hi(r.w);
    }
    v0 = fmaxf(v0, 0.f); v1 = fmaxf(v1, 0.f); v2 = fmaxf(v2, 0.f); v3 = fmaxf(v3, 0.f);
    v4 = fmaxf(v4, 0.f); v5 = fmaxf(v5, 0.f); v6 = fmaxf(v6, 0.f); v7 = fmaxf(v7, 0.f);
    if (!LAST) {
        float s = ns[node];
        v0 *= s; v1 *= s; v2 *= s; v3 *= s; v4 *= s; v5 *= s; v6 *= s; v7 *= s;
    }
    uint4 o = make_uint4(pack2(v0, v1), pack2(v2, v3), pack2(v4, v5), pack2(v6, v7));
    *((uint4*)(outb + (size_t)node * D) + h) = o;
}

// ---- MFMA node GEMM: 64-node tile/block (4 waves x 16-row strips), K=64 ----
// bf16 input; OUTMODE: 0=f32, 2=fp8(e4m3)
template<int OUTD, bool BIAS, int OUTMODE>
__global__ __launch_bounds__(256) void k_gemm(const unsigned short* __restrict__ inb,
                                              const float* __restrict__ W,
                                              const float* __restrict__ bias,
                                              void* __restrict__ out_, int n) {
    constexpr int NT = OUTD / 16;   // n-tiles
    __shared__ unsigned short WT[OUTD][72];   // stride 72: <=2-way bank alias (free)
    int t = threadIdx.x;
    for (int i = t; i < 64 * OUTD; i += 256) {
        int k = i / OUTD, nn = i % OUTD;      // W row-major [k][nn], coalesced
        WT[nn][k] = f2bf(W[i]);
    }
    __syncthreads();
    int w = t >> 6, lane = t & 63;
    int m = lane & 15, q = lane >> 4;
    int node0 = blockIdx.x * 64 + w * 16;
    int nodeA = min(node0 + m, n - 1);
    const unsigned short* ip = inb + (size_t)nodeA * D;
    bf16x8 afr[2];
    #pragma unroll
    for (int kc = 0; kc < 2; ++kc) {
        union { bf16x8 v; uint4 u; } tmp;
        tmp.u = *(const uint4*)(ip + kc * 32 + q * 8);
        afr[kc] = tmp.v;
    }
    #pragma unroll
    for (int nt = 0; nt < NT; ++nt) {
        f32x4 acc = {0.f, 0.f, 0.f, 0.f};
        #pragma unroll
        for (int kc = 0; kc < 2; ++kc) {
            union { bf16x8 v; uint4 u; } bfr;
            bfr.u = *(const uint4*)&WT[nt * 16 + m][kc * 32 + q * 8];
            acc = __builtin_amdgcn_mfma_f32_16x16x32_bf16(afr[kc], bfr.v, acc, 0, 0, 0);
        }
        int col = nt * 16 + m;
        float bb = BIAS ? bias[col] : 0.f;
        #pragma unroll
        for (int r = 0; r < 4; ++r) {
            int node = node0 + q * 4 + r;
            if (node < n) {
                float v = acc[r] + bb;
                if (OUTMODE == 2)
                    ((unsigned char*)out_)[(size_t)node * OUTD + col] = f2fp8(v);
                else
                    ((float*)out_)[(size_t)node * OUTD + col] = v;
            }
        }
    }
}

static inline char* align_up(char* p, size_t a) {
    return (char*)(((uintptr_t)p + a - 1) & ~(uintptr_t)(a - 1));
}

extern "C" void kernel_launch(void* const* d_in, const int* in_sizes, int n_in,
                              void* d_out, int out_size, void* d_ws, size_t ws_size,
                              hipStream_t stream) {
    const float* x   = (const float*)d_in[0];
    const int*   src = (const int*)d_in[1];
    const int*   dst = (const int*)d_in[2];
    const float* ew  = (const float*)d_in[3];
    const float* Wl[4] = {(const float*)d_in[4], (const float*)d_in[6],
                          (const float*)d_in[8], (const float*)d_in[10]};
    const float* bl[4] = {(const float*)d_in[5], (const float*)d_in[7],
                          (const float*)d_in[9], (const float*)d_in[11]};
    const float* Wr = (const float*)d_in[12];
    const float* br = (const float*)d_in[13];
    const float* Wo = (const float*)d_in[14];
    const float* bo = (const float*)d_in[15];
    float* out = (float*)d_out;

    const int N = NN;
    const int E = in_sizes[1];

    // ---- workspace (256B-aligned); total ~55 MB ----
    char* p = (char*)d_ws;
    float* norm_s = (float*)p;            p = align_up(p + N * 4, 256);
    float* norm_d = (float*)p;            p = align_up(p + N * 4, 256);
    int*   rowptr = (int*)p;              p = align_up(p + (size_t)(G * RS + 80) * 4, 256);
    int*   bsum   = (int*)p;              p = align_up(p + 128 * 4, 256);
    unsigned* cw  = (unsigned*)p;         p = align_up(p + (size_t)E * 4, 256);
    unsigned short* psd   = (unsigned short*)p; p = align_up(p + (size_t)NB * RS * 2, 256);
    unsigned short* cur16 = (unsigned short*)p; p = align_up(p + (size_t)NB * RS * 2, 256);
    unsigned short* resb  = (unsigned short*)p; p = align_up(p + (size_t)N * D * 2, 256);
    // aliases: psd+cur16 region (34 MB, dead after CSR) holds xs (bf16, 12.8) + tmat (fp8, 6.4)
    unsigned short* xs   = psd;
    unsigned char*  tmat = (unsigned char*)(xs + (size_t)N * D);

    // ---- CSR build (byte partials, 16-bit cursors, 3 edge passes) ----
    k_hist<<<NB, 1024, 0, stream>>>(src, dst, psd, E);
    int nb = (N + 1023) / 1024;  // 98
    k_scan1m<<<nb, 1024, 0, stream>>>(psd, norm_s, norm_d, rowptr, bsum, N);
    k_scan3c<<<(N + 255) / 256, 256, 0, stream>>>(rowptr, bsum, psd, cur16, N, E, nb);
    k_fillsort<<<NB, 1024, 0, stream>>>(src, dst, ew, rowptr, cur16, cw, E);

    // ---- fused: res = bf16(X@Wr+br), tmat1 = fp8((ns*X)@W1) ----
    k_gemm2<<<(N + 63) / 64, 256, 0, stream>>>(x, Wr, br, Wl[0], norm_s, resb, tmat, N);

    // ---- 4 GCN layers: gather(l) -> xs, then dense GEMM -> tmat(l+1) ----
    k_gather<false><<<(N + 31) / 32, 256, 0, stream>>>(
        rowptr, cw, tmat, norm_d, norm_s, bl[0], nullptr, xs, N, E);
    k_gemm<64, false, 2><<<(N + 63) / 64, 256, 0, stream>>>(xs, Wl[1], nullptr, tmat, N);
    k_gather<false><<<(N + 31) / 32, 256, 0, stream>>>(
        rowptr, cw, tmat, norm_d, norm_s, bl[1], nullptr, xs, N, E);
    k_gemm<64, false, 2><<<(N + 63) / 64, 256, 0, stream>>>(xs, Wl[2], nullptr, tmat, N);
    k_gather<false><<<(N + 31) / 32, 256, 0, stream>>>(
        rowptr, cw, tmat, norm_d, norm_s, bl[2], nullptr, xs, N, E);
    k_gemm<64, false, 2><<<(N + 63) / 64, 256, 0, stream>>>(xs, Wl[3], nullptr, tmat, N);
    k_gather<true><<<(N + 31) / 32, 256, 0, stream>>>(
        rowptr, cw, tmat, norm_d, nullptr, bl[3], resb, xs, N, E);
    // ---- out = h4 @ Wo + bo (MFMA) ----
    k_gemm<32, true, 0><<<(N + 63) / 64, 256, 0, stream>>>(xs, Wo, bo, out, N);
}

// Round 14
// 298.974 us; speedup vs baseline: 1.0626x; 1.0626x over previous
//
#include <hip/hip_runtime.h>

#define NN 100000
#define D 64
#define G 3        // node-range groups (hist/fill)
#define RS 33334   // nodes per range (G*RS >= NN)
#define NC 85      // edge chunks
#define NB (G*NC)  // 255 blocks for hist/fill

typedef short bf16x8 __attribute__((ext_vector_type(8)));
typedef float f32x4 __attribute__((ext_vector_type(4)));
typedef float f32x2 __attribute__((ext_vector_type(2)));

// ---- bf16 helpers ----
__device__ __forceinline__ float bf2f_lo(unsigned w) { return __uint_as_float(w << 16); }
__device__ __forceinline__ float bf2f_hi(unsigned w) { return __uint_as_float(w & 0xffff0000u); }
__device__ __forceinline__ unsigned short f2bf(float f) {
    unsigned u = __float_as_uint(f);
    return (unsigned short)((u + 0x7fffu + ((u >> 16) & 1u)) >> 16);
}
__device__ __forceinline__ unsigned pack2(float a, float b) {
    return (unsigned)f2bf(a) | ((unsigned)f2bf(b) << 16);
}
// ---- fp8 e4m3 helpers (HW cvt) ----
__device__ __forceinline__ unsigned char f2fp8(float v) {
    return (unsigned char)(__builtin_amdgcn_cvt_pk_fp8_f32(v, v, 0, false) & 0xff);
}
// ---- packed edge record: bits 0-16 = src, bits 17-31 = bf16(w) sans sign ----
__device__ __forceinline__ unsigned pack_cw(int s, float w) {
    return ((unsigned)f2bf(w) << 17) | (unsigned)s;
}
// ---- packed f32 FMA: acc += w2 * p (VOP3P v_pk_fma_f32) ----
#define PKFMA(acc, w2, p) \
    asm("v_pk_fma_f32 %0, %1, %2, %0" : "+v"(acc) : "v"(w2), "v"(p))

// ---- byte-packed LDS histogram: word k = nodes 2k,2k+1; per node (src,dst) bytes ----
__global__ __launch_bounds__(1024) void k_hist(const int* __restrict__ src,
                                               const int* __restrict__ dst,
                                               unsigned short* __restrict__ psd, int E) {
    __shared__ unsigned h[RS / 2];
    int b = blockIdx.x, t = threadIdx.x;
    int g = b / NC, c = b - g * NC;
    int lo = g * RS;
    for (int i = t; i < RS / 2; i += 1024) h[i] = 0;
    __syncthreads();
    int e0 = (int)((((long long)c * E / NC)) & ~3LL);
    int e1 = (c == NC - 1) ? E : (int)((((long long)(c + 1) * E / NC)) & ~3LL);
    int m = (e1 - e0) & ~4095;
    for (int e = e0 + t * 4; e < e0 + m; e += 4096) {
        int4 s4 = *(const int4*)(src + e);
        int4 d4 = *(const int4*)(dst + e);
        int v;
        v = s4.x - lo; if ((unsigned)v < RS) atomicAdd(&h[v >> 1], 1u << ((v & 1) * 16));
        v = s4.y - lo; if ((unsigned)v < RS) atomicAdd(&h[v >> 1], 1u << ((v & 1) * 16));
        v = s4.z - lo; if ((unsigned)v < RS) atomicAdd(&h[v >> 1], 1u << ((v & 1) * 16));
        v = s4.w - lo; if ((unsigned)v < RS) atomicAdd(&h[v >> 1], 1u << ((v & 1) * 16));
        v = d4.x - lo; if ((unsigned)v < RS) atomicAdd(&h[v >> 1], 1u << ((v & 1) * 16 + 8));
        v = d4.y - lo; if ((unsigned)v < RS) atomicAdd(&h[v >> 1], 1u << ((v & 1) * 16 + 8));
        v = d4.z - lo; if ((unsigned)v < RS) atomicAdd(&h[v >> 1], 1u << ((v & 1) * 16 + 8));
        v = d4.w - lo; if ((unsigned)v < RS) atomicAdd(&h[v >> 1], 1u << ((v & 1) * 16 + 8));
    }
    for (int e = e0 + m + t; e < e1; e += 1024) {
        int v = src[e] - lo; if ((unsigned)v < RS) atomicAdd(&h[v >> 1], 1u << ((v & 1) * 16));
        v = dst[e] - lo;     if ((unsigned)v < RS) atomicAdd(&h[v >> 1], 1u << ((v & 1) * 16 + 8));
    }
    __syncthreads();
    unsigned* pb = (unsigned*)(psd + (size_t)b * RS);
    for (int i = t; i < RS / 2; i += 1024) pb[i] = h[i];
}

// ---- merge byte partials -> norms + cur16 (dst running prefix per chunk); ----
// ---- block-scan 1024 in-degrees -> rowptr partial ----
__global__ __launch_bounds__(1024) void k_scan1m(const unsigned short* __restrict__ psd,
                                                 float* __restrict__ ns, float* __restrict__ nd,
                                                 int* __restrict__ rowptr,
                                                 int* __restrict__ bsum,
                                                 unsigned short* __restrict__ cur16, int n) {
    __shared__ int lds[1024];
    int t = threadIdx.x;
    int i = blockIdx.x * 1024 + t;
    int sv = 0, dv = 0;
    if (i < n) {
        int g = i / RS, off = i - g * RS;
        const unsigned short* p = psd + (size_t)(g * NC) * RS + off;
        unsigned short* cp = cur16 + (size_t)(g * NC) * RS + off;
        #pragma unroll 5
        for (int c = 0; c < NC; ++c) {
            unsigned v = p[(size_t)c * RS];
            cp[(size_t)c * RS] = (unsigned short)dv;   // dst prefix BEFORE chunk c
            sv += (int)(v & 0xffu);
            dv += (int)(v >> 8);
        }
        ns[i] = rsqrtf(fmaxf((float)sv, 1.0f));
        nd[i] = rsqrtf(fmaxf((float)dv, 1.0f));
    }
    lds[t] = dv;
    __syncthreads();
    for (int off = 1; off < 1024; off <<= 1) {
        int v = lds[t];
        int a = (t >= off) ? lds[t - off] : 0;
        __syncthreads();
        lds[t] = v + a;
        __syncthreads();
    }
    if (t == 1023) bsum[blockIdx.x] = lds[1023];
    if (i < n) rowptr[i] = lds[t] - dv;   // exclusive
}

// ---- finalize rowptr with bsum prefix (cur16 produced by k_scan1m) ----
__global__ void k_scan3c(int* __restrict__ rowptr, const int* __restrict__ bsum,
                         int n, int E, int nb) {
    __shared__ int sbs[128];
    int t = threadIdx.x;
    if (t < 128) sbs[t] = (t < nb) ? bsum[t] : 0;
    __syncthreads();
    for (int off = 1; off < 128; off <<= 1) {
        int v = 0, a = 0;
        if (t < 128) { v = sbs[t]; if (t >= off) a = sbs[t - off]; }
        __syncthreads();
        if (t < 128) sbs[t] = v + a;
        __syncthreads();
    }
    int i = blockIdx.x * blockDim.x + t;
    if (i == 0) rowptr[n] = E;
    if (i >= n) return;
    int blk = i >> 10;
    int base = (blk > 0) ? sbs[blk - 1] : 0;
    rowptr[i] += base;
}

// ---- counting-sort fill: LDS cursors = rowptr + 16-bit offsets; 4B packed records ----
__global__ __launch_bounds__(1024) void k_fillsort(const int* __restrict__ src,
                                                   const int* __restrict__ dst,
                                                   const float* __restrict__ ew,
                                                   const int* __restrict__ rowptr,
                                                   const unsigned short* __restrict__ cur16,
                                                   unsigned* __restrict__ cw, int E) {
    __shared__ int cur[RS];
    int b = blockIdx.x, t = threadIdx.x;
    int g = b / NC, c = b - g * NC;
    int lo = g * RS;
    const unsigned short* c16 = cur16 + (size_t)b * RS;
    for (int i = t; i < RS; i += 1024) cur[i] = rowptr[lo + i] + (int)c16[i];
    __syncthreads();
    int e0 = (int)((((long long)c * E / NC)) & ~3LL);
    int e1 = (c == NC - 1) ? E : (int)((((long long)(c + 1) * E / NC)) & ~3LL);
    int m = (e1 - e0) & ~4095;
    for (int e = e0 + t * 4; e < e0 + m; e += 4096) {
        int4 s4 = *(const int4*)(src + e);
        int4 d4 = *(const int4*)(dst + e);
        float4 w4 = *(const float4*)(ew + e);
        int d;
        d = d4.x - lo; if ((unsigned)d < RS) { int p = atomicAdd(&cur[d], 1); cw[p] = pack_cw(s4.x, w4.x); }
        d = d4.y - lo; if ((unsigned)d < RS) { int p = atomicAdd(&cur[d], 1); cw[p] = pack_cw(s4.y, w4.y); }
        d = d4.z - lo; if ((unsigned)d < RS) { int p = atomicAdd(&cur[d], 1); cw[p] = pack_cw(s4.z, w4.z); }
        d = d4.w - lo; if ((unsigned)d < RS) { int p = atomicAdd(&cur[d], 1); cw[p] = pack_cw(s4.w, w4.w); }
    }
    for (int e = e0 + m + t; e < e1; e += 1024) {
        int d = dst[e] - lo;
        if ((unsigned)d < RS) {
            int p = atomicAdd(&cur[d], 1);
            cw[p] = pack_cw(src[e], ew[e]);
        }
    }
}

// ---- fused first stage: res = bf16(X@Wr + br), tmat1 = fp8((ns*X)@W1) ----
__global__ __launch_bounds__(256) void k_gemm2(const float* __restrict__ x,
                                               const float* __restrict__ Wr,
                                               const float* __restrict__ brs,
                                               const float* __restrict__ W1,
                                               const float* __restrict__ ns,
                                               unsigned short* __restrict__ resb,
                                               unsigned char* __restrict__ tmat, int n) {
    __shared__ unsigned short WTr[64][72];
    __shared__ unsigned short WT1[64][72];
    int t = threadIdx.x;
    for (int i = t; i < 64 * 64; i += 256) {
        int k = i >> 6, nn = i & 63;      // W row-major [k][nn], coalesced
        WTr[nn][k] = f2bf(Wr[i]);
        WT1[nn][k] = f2bf(W1[i]);
    }
    __syncthreads();
    int w = t >> 6, lane = t & 63;
    int m = lane & 15, q = lane >> 4;
    int node0 = blockIdx.x * 64 + w * 16;
    int nodeA = min(node0 + m, n - 1);
    const float* inf = x + (size_t)nodeA * D;
    float sc = ns[nodeA];
    bf16x8 afr[2], afs[2];
    #pragma unroll
    for (int kc = 0; kc < 2; ++kc) {
        float4 f0 = *(const float4*)(inf + kc * 32 + q * 8);
        float4 f1 = *(const float4*)(inf + kc * 32 + q * 8 + 4);
        union { bf16x8 v; unsigned short u[8]; } ta, ts;
        ta.u[0] = f2bf(f0.x); ta.u[1] = f2bf(f0.y);
        ta.u[2] = f2bf(f0.z); ta.u[3] = f2bf(f0.w);
        ta.u[4] = f2bf(f1.x); ta.u[5] = f2bf(f1.y);
        ta.u[6] = f2bf(f1.z); ta.u[7] = f2bf(f1.w);
        ts.u[0] = f2bf(f0.x * sc); ts.u[1] = f2bf(f0.y * sc);
        ts.u[2] = f2bf(f0.z * sc); ts.u[3] = f2bf(f0.w * sc);
        ts.u[4] = f2bf(f1.x * sc); ts.u[5] = f2bf(f1.y * sc);
        ts.u[6] = f2bf(f1.z * sc); ts.u[7] = f2bf(f1.w * sc);
        afr[kc] = ta.v;
        afs[kc] = ts.v;
    }
    #pragma unroll
    for (int nt = 0; nt < 4; ++nt) {
        f32x4 ar = {0.f, 0.f, 0.f, 0.f};
        f32x4 at = {0.f, 0.f, 0.f, 0.f};
        #pragma unroll
        for (int kc = 0; kc < 2; ++kc) {
            union { bf16x8 v; uint4 u; } bfr, bf1;
            bfr.u = *(const uint4*)&WTr[nt * 16 + m][kc * 32 + q * 8];
            bf1.u = *(const uint4*)&WT1[nt * 16 + m][kc * 32 + q * 8];
            ar = __builtin_amdgcn_mfma_f32_16x16x32_bf16(afr[kc], bfr.v, ar, 0, 0, 0);
            at = __builtin_amdgcn_mfma_f32_16x16x32_bf16(afs[kc], bf1.v, at, 0, 0, 0);
        }
        int col = nt * 16 + m;
        float bb = brs[col];
        #pragma unroll
        for (int r = 0; r < 4; ++r) {
            int node = node0 + q * 4 + r;
            if (node < n) {
                resb[(size_t)node * D + col] = f2bf(ar[r] + bb);
                tmat[(size_t)node * D + col] = f2fp8(at[r]);
            }
        }
    }
}

// ---- gather-reduce + epilogue: 8 LANES per node (8 nodes/wave), 8-edge-deep loop;
// ---- 8 rows in flight per group; cw prefetched one iteration ahead; pk_fma ----
// invalid slots load cv=0 -> tmat row 0 (L2-hot) with w=0
template<bool LAST>
__global__ void k_gather(const int* __restrict__ rowptr, const unsigned* __restrict__ cw,
                         const unsigned char* __restrict__ tmat,
                         const float* __restrict__ nd, const float* __restrict__ ns,
                         const float* __restrict__ bias,
                         const unsigned short* __restrict__ resb,
                         unsigned short* __restrict__ outb, int n, int E) {
    int grp = threadIdx.x >> 3;            // node group in block (0..31)
    int h   = threadIdx.x & 7;             // feature octet
    int node = blockIdx.x * 32 + grp;
    bool valid = node < n;
    int nc = valid ? node : 0;
    int beg = rowptr[nc];
    int end = valid ? rowptr[nc + 1] : beg;
    unsigned h8 = (unsigned)(h * 8);
    f32x2 A0={0.f,0.f},A1={0.f,0.f},A2={0.f,0.f},A3={0.f,0.f};
    f32x2 C0={0.f,0.f},C1={0.f,0.f},C2={0.f,0.f},C3={0.f,0.f};
    unsigned cv0 = (beg     < end) ? cw[beg]     : 0u;
    unsigned cv1 = (beg + 1 < end) ? cw[beg + 1] : 0u;
    unsigned cv2 = (beg + 2 < end) ? cw[beg + 2] : 0u;
    unsigned cv3 = (beg + 3 < end) ? cw[beg + 3] : 0u;
    unsigned cv4 = (beg + 4 < end) ? cw[beg + 4] : 0u;
    unsigned cv5 = (beg + 5 < end) ? cw[beg + 5] : 0u;
    unsigned cv6 = (beg + 6 < end) ? cw[beg + 6] : 0u;
    unsigned cv7 = (beg + 7 < end) ? cw[beg + 7] : 0u;
    for (int e = beg; e < end; e += 8) {
        // 8 tmat rows in flight (uniform base + 32-bit voffset)
        uint2 r0 = *(const uint2*)(tmat + (((cv0 & 0x1FFFFu) << 6) + h8));
        uint2 r1 = *(const uint2*)(tmat + (((cv1 & 0x1FFFFu) << 6) + h8));
        uint2 r2 = *(const uint2*)(tmat + (((cv2 & 0x1FFFFu) << 6) + h8));
        uint2 r3 = *(const uint2*)(tmat + (((cv3 & 0x1FFFFu) << 6) + h8));
        uint2 r4 = *(const uint2*)(tmat + (((cv4 & 0x1FFFFu) << 6) + h8));
        uint2 r5 = *(const uint2*)(tmat + (((cv5 & 0x1FFFFu) << 6) + h8));
        uint2 r6 = *(const uint2*)(tmat + (((cv6 & 0x1FFFFu) << 6) + h8));
        uint2 r7 = *(const uint2*)(tmat + (((cv7 & 0x1FFFFu) << 6) + h8));
        // weights decoded before cv regs are overwritten by prefetch
        float w0 = __uint_as_float((cv0 >> 17) << 16);
        float w1 = __uint_as_float((cv1 >> 17) << 16);
        float w2 = __uint_as_float((cv2 >> 17) << 16);
        float w3 = __uint_as_float((cv3 >> 17) << 16);
        float w4 = __uint_as_float((cv4 >> 17) << 16);
        float w5 = __uint_as_float((cv5 >> 17) << 16);
        float w6 = __uint_as_float((cv6 >> 17) << 16);
        float w7 = __uint_as_float((cv7 >> 17) << 16);
        // prefetch next iteration's edge records
        int f = e + 8;
        cv0 = (f     < end) ? cw[f]     : 0u;
        cv1 = (f + 1 < end) ? cw[f + 1] : 0u;
        cv2 = (f + 2 < end) ? cw[f + 2] : 0u;
        cv3 = (f + 3 < end) ? cw[f + 3] : 0u;
        cv4 = (f + 4 < end) ? cw[f + 4] : 0u;
        cv5 = (f + 5 < end) ? cw[f + 5] : 0u;
        cv6 = (f + 6 < end) ? cw[f + 6] : 0u;
        cv7 = (f + 7 < end) ? cw[f + 7] : 0u;
        f32x2 p, wv;
        wv.x = w0; wv.y = w0;
        p = __builtin_amdgcn_cvt_pk_f32_fp8(r0.x, false); PKFMA(A0, wv, p);
        p = __builtin_amdgcn_cvt_pk_f32_fp8(r0.x, true);  PKFMA(A1, wv, p);
        p = __builtin_amdgcn_cvt_pk_f32_fp8(r0.y, false); PKFMA(A2, wv, p);
        p = __builtin_amdgcn_cvt_pk_f32_fp8(r0.y, true);  PKFMA(A3, wv, p);
        wv.x = w1; wv.y = w1;
        p = __builtin_amdgcn_cvt_pk_f32_fp8(r1.x, false); PKFMA(C0, wv, p);
        p = __builtin_amdgcn_cvt_pk_f32_fp8(r1.x, true);  PKFMA(C1, wv, p);
        p = __builtin_amdgcn_cvt_pk_f32_fp8(r1.y, false); PKFMA(C2, wv, p);
        p = __builtin_amdgcn_cvt_pk_f32_fp8(r1.y, true);  PKFMA(C3, wv, p);
        wv.x = w2; wv.y = w2;
        p = __builtin_amdgcn_cvt_pk_f32_fp8(r2.x, false); PKFMA(A0, wv, p);
        p = __builtin_amdgcn_cvt_pk_f32_fp8(r2.x, true);  PKFMA(A1, wv, p);
        p = __builtin_amdgcn_cvt_pk_f32_fp8(r2.y, false); PKFMA(A2, wv, p);
        p = __builtin_amdgcn_cvt_pk_f32_fp8(r2.y, true);  PKFMA(A3, wv, p);
        wv.x = w3; wv.y = w3;
        p = __builtin_amdgcn_cvt_pk_f32_fp8(r3.x, false); PKFMA(C0, wv, p);
        p = __builtin_amdgcn_cvt_pk_f32_fp8(r3.x, true);  PKFMA(C1, wv, p);
        p = __builtin_amdgcn_cvt_pk_f32_fp8(r3.y, false); PKFMA(C2, wv, p);
        p = __builtin_amdgcn_cvt_pk_f32_fp8(r3.y, true);  PKFMA(C3, wv, p);
        wv.x = w4; wv.y = w4;
        p = __builtin_amdgcn_cvt_pk_f32_fp8(r4.x, false); PKFMA(A0, wv, p);
        p = __builtin_amdgcn_cvt_pk_f32_fp8(r4.x, true);  PKFMA(A1, wv, p);
        p = __builtin_amdgcn_cvt_pk_f32_fp8(r4.y, false); PKFMA(A2, wv, p);
        p = __builtin_amdgcn_cvt_pk_f32_fp8(r4.y, true);  PKFMA(A3, wv, p);
        wv.x = w5; wv.y = w5;
        p = __builtin_amdgcn_cvt_pk_f32_fp8(r5.x, false); PKFMA(C0, wv, p);
        p = __builtin_amdgcn_cvt_pk_f32_fp8(r5.x, true);  PKFMA(C1, wv, p);
        p = __builtin_amdgcn_cvt_pk_f32_fp8(r5.y, false); PKFMA(C2, wv, p);
        p = __builtin_amdgcn_cvt_pk_f32_fp8(r5.y, true);  PKFMA(C3, wv, p);
        wv.x = w6; wv.y = w6;
        p = __builtin_amdgcn_cvt_pk_f32_fp8(r6.x, false); PKFMA(A0, wv, p);
        p = __builtin_amdgcn_cvt_pk_f32_fp8(r6.x, true);  PKFMA(A1, wv, p);
        p = __builtin_amdgcn_cvt_pk_f32_fp8(r6.y, false); PKFMA(A2, wv, p);
        p = __builtin_amdgcn_cvt_pk_f32_fp8(r6.y, true);  PKFMA(A3, wv, p);
        wv.x = w7; wv.y = w7;
        p = __builtin_amdgcn_cvt_pk_f32_fp8(r7.x, false); PKFMA(C0, wv, p);
        p = __builtin_amdgcn_cvt_pk_f32_fp8(r7.x, true);  PKFMA(C1, wv, p);
        p = __builtin_amdgcn_cvt_pk_f32_fp8(r7.y, false); PKFMA(C2, wv, p);
        p = __builtin_amdgcn_cvt_pk_f32_fp8(r7.y, true);  PKFMA(C3, wv, p);
    }
    if (!valid) return;
    float a0 = A0.x + C0.x, a1 = A0.y + C0.y;
    float a2 = A1.x + C1.x, a3 = A1.y + C1.y;
    float a4 = A2.x + C2.x, a5 = A2.y + C2.y;
    float a6 = A3.x + C3.x, a7 = A3.y + C3.y;
    float ndv = nd[node];
    float4 b0 = *(const float4*)(bias + 8 * h);
    float4 b1 = *(const float4*)(bias + 8 * h + 4);
    float v0 = ndv * a0 + b0.x, v1 = ndv * a1 + b0.y;
    float v2 = ndv * a2 + b0.z, v3 = ndv * a3 + b0.w;
    float v4 = ndv * a4 + b1.x, v5 = ndv * a5 + b1.y;
    float v6 = ndv * a6 + b1.z, v7 = ndv * a7 + b1.w;
    if (LAST) {
        uint4 r = *((const uint4*)(resb + (size_t)node * D) + h);
        v0 += bf2f_lo(r.x); v1 += bf2f_hi(r.x);
        v2 += bf2f_lo(r.y); v3 += bf2f_hi(r.y);
        v4 += bf2f_lo(r.z); v5 += bf2f_hi(r.z);
        v6 += bf2f_lo(r.w); v7 += bf2f_hi(r.w);
    }
    v0 = fmaxf(v0, 0.f); v1 = fmaxf(v1, 0.f); v2 = fmaxf(v2, 0.f); v3 = fmaxf(v3, 0.f);
    v4 = fmaxf(v4, 0.f); v5 = fmaxf(v5, 0.f); v6 = fmaxf(v6, 0.f); v7 = fmaxf(v7, 0.f);
    if (!LAST) {
        float s = ns[node];
        v0 *= s; v1 *= s; v2 *= s; v3 *= s; v4 *= s; v5 *= s; v6 *= s; v7 *= s;
    }
    uint4 o = make_uint4(pack2(v0, v1), pack2(v2, v3), pack2(v4, v5), pack2(v6, v7));
    *((uint4*)(outb + (size_t)node * D) + h) = o;
}

// ---- MFMA node GEMM: 64-node tile/block (4 waves x 16-row strips), K=64 ----
// bf16 input; OUTMODE: 0=f32, 2=fp8(e4m3)
template<int OUTD, bool BIAS, int OUTMODE>
__global__ __launch_bounds__(256) void k_gemm(const unsigned short* __restrict__ inb,
                                              const float* __restrict__ W,
                                              const float* __restrict__ bias,
                                              void* __restrict__ out_, int n) {
    constexpr int NT = OUTD / 16;   // n-tiles
    __shared__ unsigned short WT[OUTD][72];   // stride 72: <=2-way bank alias (free)
    int t = threadIdx.x;
    for (int i = t; i < 64 * OUTD; i += 256) {
        int k = i / OUTD, nn = i % OUTD;      // W row-major [k][nn], coalesced
        WT[nn][k] = f2bf(W[i]);
    }
    __syncthreads();
    int w = t >> 6, lane = t & 63;
    int m = lane & 15, q = lane >> 4;
    int node0 = blockIdx.x * 64 + w * 16;
    int nodeA = min(node0 + m, n - 1);
    const unsigned short* ip = inb + (size_t)nodeA * D;
    bf16x8 afr[2];
    #pragma unroll
    for (int kc = 0; kc < 2; ++kc) {
        union { bf16x8 v; uint4 u; } tmp;
        tmp.u = *(const uint4*)(ip + kc * 32 + q * 8);
        afr[kc] = tmp.v;
    }
    #pragma unroll
    for (int nt = 0; nt < NT; ++nt) {
        f32x4 acc = {0.f, 0.f, 0.f, 0.f};
        #pragma unroll
        for (int kc = 0; kc < 2; ++kc) {
            union { bf16x8 v; uint4 u; } bfr;
            bfr.u = *(const uint4*)&WT[nt * 16 + m][kc * 32 + q * 8];
            acc = __builtin_amdgcn_mfma_f32_16x16x32_bf16(afr[kc], bfr.v, acc, 0, 0, 0);
        }
        int col = nt * 16 + m;
        float bb = BIAS ? bias[col] : 0.f;
        #pragma unroll
        for (int r = 0; r < 4; ++r) {
            int node = node0 + q * 4 + r;
            if (node < n) {
                float v = acc[r] + bb;
                if (OUTMODE == 2)
                    ((unsigned char*)out_)[(size_t)node * OUTD + col] = f2fp8(v);
                else
                    ((float*)out_)[(size_t)node * OUTD + col] = v;
            }
        }
    }
}

static inline char* align_up(char* p, size_t a) {
    return (char*)(((uintptr_t)p + a - 1) & ~(uintptr_t)(a - 1));
}

extern "C" void kernel_launch(void* const* d_in, const int* in_sizes, int n_in,
                              void* d_out, int out_size, void* d_ws, size_t ws_size,
                              hipStream_t stream) {
    const float* x   = (const float*)d_in[0];
    const int*   src = (const int*)d_in[1];
    const int*   dst = (const int*)d_in[2];
    const float* ew  = (const float*)d_in[3];
    const float* Wl[4] = {(const float*)d_in[4], (const float*)d_in[6],
                          (const float*)d_in[8], (const float*)d_in[10]};
    const float* bl[4] = {(const float*)d_in[5], (const float*)d_in[7],
                          (const float*)d_in[9], (const float*)d_in[11]};
    const float* Wr = (const float*)d_in[12];
    const float* br = (const float*)d_in[13];
    const float* Wo = (const float*)d_in[14];
    const float* bo = (const float*)d_in[15];
    float* out = (float*)d_out;

    const int N = NN;
    const int E = in_sizes[1];

    // ---- workspace (256B-aligned); total ~55 MB ----
    char* p = (char*)d_ws;
    float* norm_s = (float*)p;            p = align_up(p + N * 4, 256);
    float* norm_d = (float*)p;            p = align_up(p + N * 4, 256);
    int*   rowptr = (int*)p;              p = align_up(p + (size_t)(G * RS + 80) * 4, 256);
    int*   bsum   = (int*)p;              p = align_up(p + 128 * 4, 256);
    unsigned* cw  = (unsigned*)p;         p = align_up(p + (size_t)E * 4, 256);
    unsigned short* psd   = (unsigned short*)p; p = align_up(p + (size_t)NB * RS * 2, 256);
    unsigned short* cur16 = (unsigned short*)p; p = align_up(p + (size_t)NB * RS * 2, 256);
    unsigned short* resb  = (unsigned short*)p; p = align_up(p + (size_t)N * D * 2, 256);
    // aliases: psd+cur16 region (34 MB, dead after CSR) holds xs (bf16, 12.8) + tmat (fp8, 6.4)
    unsigned short* xs   = psd;
    unsigned char*  tmat = (unsigned char*)(xs + (size_t)N * D);

    // ---- CSR build (byte partials, cur16 fused into scan1m, 3 edge passes) ----
    k_hist<<<NB, 1024, 0, stream>>>(src, dst, psd, E);
    int nb = (N + 1023) / 1024;  // 98
    k_scan1m<<<nb, 1024, 0, stream>>>(psd, norm_s, norm_d, rowptr, bsum, cur16, N);
    k_scan3c<<<(N + 255) / 256, 256, 0, stream>>>(rowptr, bsum, N, E, nb);
    k_fillsort<<<NB, 1024, 0, stream>>>(src, dst, ew, rowptr, cur16, cw, E);

    // ---- fused: res = bf16(X@Wr+br), tmat1 = fp8((ns*X)@W1) ----
    k_gemm2<<<(N + 63) / 64, 256, 0, stream>>>(x, Wr, br, Wl[0], norm_s, resb, tmat, N);

    // ---- 4 GCN layers: gather(l) -> xs, then dense GEMM -> tmat(l+1) ----
    k_gather<false><<<(N + 31) / 32, 256, 0, stream>>>(
        rowptr, cw, tmat, norm_d, norm_s, bl[0], nullptr, xs, N, E);
    k_gemm<64, false, 2><<<(N + 63) / 64, 256, 0, stream>>>(xs, Wl[1], nullptr, tmat, N);
    k_gather<false><<<(N + 31) / 32, 256, 0, stream>>>(
        rowptr, cw, tmat, norm_d, norm_s, bl[1], nullptr, xs, N, E);
    k_gemm<64, false, 2><<<(N + 63) / 64, 256, 0, stream>>>(xs, Wl[2], nullptr, tmat, N);
    k_gather<false><<<(N + 31) / 32, 256, 0, stream>>>(
        rowptr, cw, tmat, norm_d, norm_s, bl[2], nullptr, xs, N, E);
    k_gemm<64, false, 2><<<(N + 63) / 64, 256, 0, stream>>>(xs, Wl[3], nullptr, tmat, N);
    k_gather<true><<<(N + 31) / 32, 256, 0, stream>>>(
        rowptr, cw, tmat, norm_d, nullptr, bl[3], resb, xs, N, E);
    // ---- out = h4 @ Wo + bo (MFMA) ----
    k_gemm<32, true, 0><<<(N + 63) / 64, 256, 0, stream>>>(xs, Wo, bo, out, N);
}